// Round 1
// baseline (179095.984 us; speedup 1.0000x reference)
//
#include <hip/hip_runtime.h>
#include <math.h>

#define TT 2048
#define BB 128

__device__ __forceinline__ float sigf(float x) {
    return 1.0f / (1.0f + __expf(-x));
}

// Generic LSTM layer step. DIN = input dim, DH = hidden dim.
// x: DIN floats (LDS or global, wave-uniform reads ok)
// hh/cc: DH floats in LDS (state, updated in place)
// gates: scratch LDS, >= 4*DH floats
template<int DIN, int DH>
__device__ __forceinline__ void lstm_layer(
    const float* __restrict__ wih, const float* __restrict__ whh,
    const float* __restrict__ bih, const float* __restrict__ bhh,
    const float* __restrict__ x,
    float* __restrict__ hh, float* __restrict__ cc,
    float* __restrict__ gates, int tid)
{
    constexpr int G = 4 * DH;
    constexpr int R = (G + 255) / 256;   // gate rows per thread

    float acc[R];
#pragma unroll
    for (int r = 0; r < R; ++r) {
        int j = tid + r * 256;
        acc[r] = (j < G) ? (bih[j] + bhh[j]) : 0.f;
    }

    // input contribution
    if constexpr (DIN >= 4) {
        const float4* xv = (const float4*)x;
        for (int k = 0; k < DIN / 4; ++k) {
            float4 xx = xv[k];
#pragma unroll
            for (int r = 0; r < R; ++r) {
                int j = tid + r * 256;
                if (j < G) {
                    float4 w = ((const float4*)(wih + (size_t)j * DIN))[k];
                    acc[r] += w.x * xx.x + w.y * xx.y + w.z * xx.z + w.w * xx.w;
                }
            }
        }
    } else {
        float xx = x[0];
#pragma unroll
        for (int r = 0; r < R; ++r) {
            int j = tid + r * 256;
            if (j < G) acc[r] += xx * wih[j];   // DIN == 1
        }
    }

    // recurrent contribution
    {
        const float4* hv = (const float4*)hh;
        for (int k = 0; k < DH / 4; ++k) {
            float4 hx = hv[k];
#pragma unroll
            for (int r = 0; r < R; ++r) {
                int j = tid + r * 256;
                if (j < G) {
                    float4 w = ((const float4*)(whh + (size_t)j * DH))[k];
                    acc[r] += w.x * hx.x + w.y * hx.y + w.z * hx.z + w.w * hx.w;
                }
            }
        }
    }

#pragma unroll
    for (int r = 0; r < R; ++r) {
        int j = tid + r * 256;
        if (j < G) gates[j] = acc[r];
    }
    __syncthreads();   // all reads of hh done; gates visible

    if (tid < DH) {
        float ig = sigf(gates[tid]);
        float fg = sigf(gates[DH + tid]);
        float gg = tanhf(gates[2 * DH + tid]);
        float og = sigf(gates[3 * DH + tid]);
        float cn = fg * cc[tid] + ig * gg;
        cc[tid] = cn;
        hh[tid] = og * tanhf(cn);
    }
    __syncthreads();   // new h visible to next layer
}

__global__ __launch_bounds__(256)
void lstm_seq_kernel(
    const float* __restrict__ inp,
    const float* __restrict__ w1ih, const float* __restrict__ w1hh,
    const float* __restrict__ b1ih, const float* __restrict__ b1hh,
    const float* __restrict__ w2ih, const float* __restrict__ w2hh,
    const float* __restrict__ b2ih, const float* __restrict__ b2hh,
    const float* __restrict__ w3ih, const float* __restrict__ w3hh,
    const float* __restrict__ b3ih, const float* __restrict__ b3hh,
    const float* __restrict__ w4ih, const float* __restrict__ w4hh,
    const float* __restrict__ b4ih, const float* __restrict__ b4hh,
    const float* __restrict__ w5ih, const float* __restrict__ w5hh,
    const float* __restrict__ b5ih, const float* __restrict__ b5hh,
    const float* __restrict__ wlin, const float* __restrict__ blin,
    float* __restrict__ out)
{
    // h/c layout: L1 @0 (256), L2 @256 (128), L3 @384 (64), L4 @448 (32), L5 @480 (16)
    __shared__ __align__(16) float h[512];
    __shared__ __align__(16) float c[512];
    __shared__ __align__(16) float gates[1024];

    const int tid = threadIdx.x;
    const int b = blockIdx.x;

    for (int i = tid; i < 512; i += 256) { h[i] = 0.f; c[i] = 0.f; }
    __syncthreads();

    const float* xin = inp + (size_t)b * TT;

    for (int t = 0; t < TT; ++t) {
        lstm_layer<1,   256>(w1ih, w1hh, b1ih, b1hh, xin + t, h + 0,   c + 0,   gates, tid);
        lstm_layer<256, 128>(w2ih, w2hh, b2ih, b2hh, h + 0,   h + 256, c + 256, gates, tid);
        lstm_layer<128, 64 >(w3ih, w3hh, b3ih, b3hh, h + 256, h + 384, c + 384, gates, tid);
        lstm_layer<64,  32 >(w4ih, w4hh, b4ih, b4hh, h + 384, h + 448, c + 448, gates, tid);
        lstm_layer<32,  16 >(w5ih, w5hh, b5ih, b5hh, h + 448, h + 480, c + 480, gates, tid);

        if (tid == 0) {
            float acc = blin[0];
#pragma unroll
            for (int k = 0; k < 16; ++k) acc += h[480 + k] * wlin[k];
            out[(size_t)b * TT + t] = acc;
        }
    }
}

extern "C" void kernel_launch(void* const* d_in, const int* in_sizes, int n_in,
                              void* d_out, int out_size, void* d_ws, size_t ws_size,
                              hipStream_t stream) {
    const float* p[23];
    for (int i = 0; i < 23 && i < n_in; ++i) p[i] = (const float*)d_in[i];

    lstm_seq_kernel<<<dim3(BB), dim3(256), 0, stream>>>(
        p[0],
        p[1],  p[2],  p[3],  p[4],
        p[5],  p[6],  p[7],  p[8],
        p[9],  p[10], p[11], p[12],
        p[13], p[14], p[15], p[16],
        p[17], p[18], p[19], p[20],
        p[21], p[22],
        (float*)d_out);
}

// Round 2
// 34986.475 us; speedup vs baseline: 5.1190x; 5.1190x over previous
//
#include <hip/hip_runtime.h>
#include <math.h>

#define TT 2048
#define BB 128

// ---- d_ws layout (floats) ----
// Wc1: [256][1024]  @ 0        (w1hh^T, k-major)    262144
// Wc2: [384][512]   @ 262144   ([w2ih^T; w2hh^T])   196608
// Wc3: [192][256]   @ 458752                         49152
// Wc4: [96][128]    @ 507904                         12288
// Wc5: [48][64]     @ 520192                          3072
// bcat:[1984]       @ 523264   (b_ih+b_hh concat)     1984
// total 525248 floats = 2.1 MB
#define WC1_OFF 0
#define WC2_OFF 262144
#define WC3_OFF 458752
#define WC4_OFF 507904
#define WC5_OFF 520192
#define BC_OFF  523264
#define WS_TOT  525248

__device__ __forceinline__ float sigf(float x) {
    return 1.0f / (1.0f + __expf(-x));
}

// ---------------- prep: transpose weights into k-major concat form ----------------
__global__ __launch_bounds__(256)
void prep_kernel(const float* __restrict__ w1hh,
                 const float* __restrict__ w2ih, const float* __restrict__ w2hh,
                 const float* __restrict__ w3ih, const float* __restrict__ w3hh,
                 const float* __restrict__ w4ih, const float* __restrict__ w4hh,
                 const float* __restrict__ w5ih, const float* __restrict__ w5hh,
                 const float* __restrict__ b1ih, const float* __restrict__ b1hh,
                 const float* __restrict__ b2ih, const float* __restrict__ b2hh,
                 const float* __restrict__ b3ih, const float* __restrict__ b3hh,
                 const float* __restrict__ b4ih, const float* __restrict__ b4hh,
                 const float* __restrict__ b5ih, const float* __restrict__ b5hh,
                 float* __restrict__ ws)
{
    int idx = blockIdx.x * 256 + threadIdx.x;
    if (idx >= WS_TOT) return;
    float v;
    if (idx < WC2_OFF) {                       // Wc1 [256][1024] = w1hh^T
        int k = idx >> 10, j = idx & 1023;
        v = w1hh[j * 256 + k];
    } else if (idx < WC3_OFF) {                // Wc2 [384][512]
        int r = idx - WC2_OFF;
        int k = r >> 9, j = r & 511;
        v = (k < 256) ? w2ih[j * 256 + k] : w2hh[j * 128 + (k - 256)];
    } else if (idx < WC4_OFF) {                // Wc3 [192][256]
        int r = idx - WC3_OFF;
        int k = r >> 8, j = r & 255;
        v = (k < 128) ? w3ih[j * 128 + k] : w3hh[j * 64 + (k - 128)];
    } else if (idx < WC5_OFF) {                // Wc4 [96][128]
        int r = idx - WC4_OFF;
        int k = r >> 7, j = r & 127;
        v = (k < 64) ? w4ih[j * 64 + k] : w4hh[j * 32 + (k - 64)];
    } else if (idx < BC_OFF) {                 // Wc5 [48][64]
        int r = idx - WC5_OFF;
        int k = r >> 6, j = r & 63;
        v = (k < 32) ? w5ih[j * 32 + k] : w5hh[j * 16 + (k - 32)];
    } else {                                   // bcat
        int r = idx - BC_OFF;
        if (r < 1024)      v = b1ih[r]        + b1hh[r];
        else if (r < 1536) v = b2ih[r - 1024] + b2hh[r - 1024];
        else if (r < 1792) v = b3ih[r - 1536] + b3hh[r - 1536];
        else if (r < 1920) v = b4ih[r - 1792] + b4hh[r - 1792];
        else               v = b5ih[r - 1920] + b5hh[r - 1920];
    }
    ws[idx] = v;
}

// ---------------- per-layer step ----------------
// KTOT rows of Wc (k-major [KTOT][G]); S k-segments; active threads = S*G/4.
// Thread (s,q) accumulates float4 of gate rows 4q..4q+3 over k-seg s.
// Combine stage: thread j<DH sums segments + bias (+ x*w1ih for L1), nonlinearity,
// updates C[COFF+j] and X[HOFF+j].
template<int KTOT, int G, int DH, int S, int XK, int HOFF, int COFF, int BOFF, bool L1X>
__device__ __forceinline__ void layer_step(
    const float4* __restrict__ Wc4,
    float* __restrict__ X, float* __restrict__ C,
    float* __restrict__ partf,
    const float* __restrict__ bc, const float* __restrict__ w1l,
    int tid)
{
    constexpr int G4 = G / 4;
    constexpr int KSEG = KTOT / S;
    static_assert(KTOT % S == 0, "even k-split");

    if (tid < S * G4) {
        int q = tid & (G4 - 1);
        int s = tid / G4;
        const float*  xp = X + XK + s * KSEG;
        const float4* wp = Wc4 + (size_t)s * KSEG * G4 + q;
        float4 a = {0.f, 0.f, 0.f, 0.f};
#pragma unroll 8
        for (int k = 0; k < KSEG; ++k) {
            float  xx = xp[k];
            float4 w  = wp[(size_t)k * G4];
            a.x = fmaf(w.x, xx, a.x);
            a.y = fmaf(w.y, xx, a.y);
            a.z = fmaf(w.z, xx, a.z);
            a.w = fmaf(w.w, xx, a.w);
        }
        ((float4*)partf)[s * G4 + q] = a;
    }
    __syncthreads();   // partials visible

    if (tid < DH) {
        float g[4];
#pragma unroll
        for (int cg = 0; cg < 4; ++cg) {
            int r = cg * DH + tid;
            float acc = bc[BOFF + r];
#pragma unroll
            for (int s2 = 0; s2 < S; ++s2) acc += partf[s2 * G + r];
            if (L1X) acc = fmaf(X[0], w1l[r], acc);
            g[cg] = acc;
        }
        float ig = sigf(g[0]), fg = sigf(g[1]);
        float gg = tanhf(g[2]), og = sigf(g[3]);
        float cn = fmaf(fg, C[COFF + tid], ig * gg);
        C[COFF + tid] = cn;
        X[HOFF + tid] = og * tanhf(cn);
    }
    // trailing __syncthreads() supplied by caller
}

// ---------------- main persistent kernel: one block per batch element ----------------
// X layout: [x_t @0, h1 @1 (256), h2 @257 (128), h3 @385 (64), h4 @449 (32), h5 @481 (16)]
__global__ __launch_bounds__(1024)
void lstm_main(const float* __restrict__ inp,
               const float* __restrict__ ws,
               const float* __restrict__ w1ih,
               const float* __restrict__ wlin, const float* __restrict__ blin,
               float* __restrict__ out)
{
    __shared__ __align__(16) float X[512];
    __shared__ __align__(16) float C[512];
    __shared__ __align__(16) float part[4096];
    __shared__ float bc[1984];
    __shared__ float w1l[1024];
    __shared__ float wl[17];

    const int tid = threadIdx.x;
    const int b = blockIdx.x;

    for (int i = tid; i < 512; i += 1024) { X[i] = 0.f; C[i] = 0.f; }
    for (int i = tid; i < 1984; i += 1024) bc[i] = ws[BC_OFF + i];
    if (tid < 1024) w1l[tid] = w1ih[tid];
    if (tid < 16) wl[tid] = wlin[tid];
    if (tid == 16) wl[16] = blin[0];
    if (tid == 0) X[0] = inp[(size_t)b * TT];
    __syncthreads();

    const float4* Wc1 = (const float4*)(ws + WC1_OFF);
    const float4* Wc2 = (const float4*)(ws + WC2_OFF);
    const float4* Wc3 = (const float4*)(ws + WC3_OFF);
    const float4* Wc4p = (const float4*)(ws + WC4_OFF);
    const float4* Wc5 = (const float4*)(ws + WC5_OFF);

    for (int t = 0; t < TT; ++t) {
        // L1: k over h1 only (x-term folded into combine via w1l)
        layer_step<256, 1024, 256,  4, 1,   1,   0,    0, true >(Wc1, X, C, part, bc, w1l, tid);
        __syncthreads();
        layer_step<384,  512, 128,  8, 1,   257, 256, 1024, false>(Wc2, X, C, part, bc, w1l, tid);
        __syncthreads();
        layer_step<192,  256,  64, 16, 257, 385, 384, 1536, false>(Wc3, X, C, part, bc, w1l, tid);
        __syncthreads();
        layer_step< 96,  128,  32,  8, 385, 449, 448, 1792, false>(Wc4p, X, C, part, bc, w1l, tid);
        __syncthreads();
        layer_step< 48,   64,  16,  8, 449, 481, 480, 1920, false>(Wc5, X, C, part, bc, w1l, tid);
        if (tid == 32) X[0] = (t + 1 < TT) ? inp[(size_t)b * TT + t + 1] : 0.f;
        __syncthreads();

        if (tid == 0) {
            float acc = wl[16];
#pragma unroll
            for (int k = 0; k < 16; ++k) acc = fmaf(X[481 + k], wl[k], acc);
            out[(size_t)b * TT + t] = acc;
        }
    }
}

extern "C" void kernel_launch(void* const* d_in, const int* in_sizes, int n_in,
                              void* d_out, int out_size, void* d_ws, size_t ws_size,
                              hipStream_t stream) {
    const float* p[23];
    for (int i = 0; i < 23 && i < n_in; ++i) p[i] = (const float*)d_in[i];
    float* ws = (float*)d_ws;

    // p: 0 inp | 1 w1ih 2 w1hh 3 b1ih 4 b1hh | 5 w2ih 6 w2hh 7 b2ih 8 b2hh |
    //    9 w3ih 10 w3hh 11 b3ih 12 b3hh | 13 w4ih 14 w4hh 15 b4ih 16 b4hh |
    //    17 w5ih 18 w5hh 19 b5ih 20 b5hh | 21 wlin 22 blin
    prep_kernel<<<dim3((WS_TOT + 255) / 256), dim3(256), 0, stream>>>(
        p[2],
        p[5],  p[6],  p[9],  p[10], p[13], p[14], p[17], p[18],
        p[3],  p[4],  p[7],  p[8],  p[11], p[12], p[15], p[16],
        p[19], p[20],
        ws);

    lstm_main<<<dim3(BB), dim3(1024), 0, stream>>>(
        p[0], ws, p[1], p[21], p[22], (float*)d_out);
}

// Round 3
// 23540.753 us; speedup vs baseline: 7.6079x; 1.4862x over previous
//
#include <hip/hip_runtime.h>
#include <math.h>

#define TT 2048
#define BB 128

typedef _Float16 half8 __attribute__((ext_vector_type(8)));

// ---- d_ws layout ----
// floats ws[0..1984):   bcat (b_ih+b_hh concat, fp32)
// halves from ws+2048 floats (byte 8192), k-major [K][G]:
//   Wc1h [256][1024] @ 0        (w1hh^T)            262144
//   Wc2h [384][512]  @ 262144   ([w2ih^T; w2hh^T])  196608
//   Wc3h [192][256]  @ 458752                        49152
//   Wc4h [96][128]   @ 507904                        12288
//   Wc5h [48][64]    @ 520192                         3072
//   total 523264 halves
#define BC_FLOATS 1984
#define H_BASE_F  2048          // float offset where half region starts
#define HC1 0
#define HC2 262144
#define HC3 458752
#define HC4 507904
#define HC5 520192
#define HTOT 523264
#define PREP_TOT (HTOT + BC_FLOATS)

__device__ __forceinline__ float sigf(float x) {
    return 1.0f / (1.0f + __expf(-x));
}

// ---------------- prep: transpose + fp16-quantize weights ----------------
__global__ __launch_bounds__(256)
void prep_kernel(const float* __restrict__ w1hh,
                 const float* __restrict__ w2ih, const float* __restrict__ w2hh,
                 const float* __restrict__ w3ih, const float* __restrict__ w3hh,
                 const float* __restrict__ w4ih, const float* __restrict__ w4hh,
                 const float* __restrict__ w5ih, const float* __restrict__ w5hh,
                 const float* __restrict__ b1ih, const float* __restrict__ b1hh,
                 const float* __restrict__ b2ih, const float* __restrict__ b2hh,
                 const float* __restrict__ b3ih, const float* __restrict__ b3hh,
                 const float* __restrict__ b4ih, const float* __restrict__ b4hh,
                 const float* __restrict__ b5ih, const float* __restrict__ b5hh,
                 float* __restrict__ ws)
{
    int idx = blockIdx.x * 256 + threadIdx.x;
    if (idx >= PREP_TOT) return;

    if (idx < HTOT) {
        _Float16* wsh = (_Float16*)(ws + H_BASE_F);
        float v;
        if (idx < HC2) {                       // Wc1 [256][1024] = w1hh^T
            int k = idx >> 10, j = idx & 1023;
            v = w1hh[j * 256 + k];
        } else if (idx < HC3) {                // Wc2 [384][512]
            int r = idx - HC2;
            int k = r >> 9, j = r & 511;
            v = (k < 256) ? w2ih[j * 256 + k] : w2hh[j * 128 + (k - 256)];
        } else if (idx < HC4) {                // Wc3 [192][256]
            int r = idx - HC3;
            int k = r >> 8, j = r & 255;
            v = (k < 128) ? w3ih[j * 128 + k] : w3hh[j * 64 + (k - 128)];
        } else if (idx < HC5) {                // Wc4 [96][128]
            int r = idx - HC4;
            int k = r >> 7, j = r & 127;
            v = (k < 64) ? w4ih[j * 64 + k] : w4hh[j * 32 + (k - 64)];
        } else {                               // Wc5 [48][64]
            int r = idx - HC5;
            int k = r >> 6, j = r & 63;
            v = (k < 32) ? w5ih[j * 32 + k] : w5hh[j * 16 + (k - 32)];
        }
        wsh[idx] = (_Float16)v;                // RN conversion
    } else {
        int r = idx - HTOT;
        float v;
        if (r < 1024)      v = b1ih[r]        + b1hh[r];
        else if (r < 1536) v = b2ih[r - 1024] + b2hh[r - 1024];
        else if (r < 1792) v = b3ih[r - 1536] + b3hh[r - 1536];
        else if (r < 1920) v = b4ih[r - 1792] + b4hh[r - 1792];
        else               v = b5ih[r - 1920] + b5hh[r - 1920];
        ws[r] = v;
    }
}

// ---------------- per-layer step (fp16 weights, fp32 math) ----------------
// Wc: k-major [KTOT][G] halves. S k-segments; thread (s,q) owns gate rows
// 8q..8q+7 over k-seg s, loads half8 (16 B) per k. Active threads = S*G/8.
// Combine: thread j<DH sums partials + bias (+ x*w1ih for L1), nonlinearity,
// updates C[COFF+j], X[HOFF+j].
template<int KTOT, int G, int DH, int S, int XK, int HOFF, int COFF, int BOFF, bool L1X>
__device__ __forceinline__ void layer_step(
    const _Float16* __restrict__ Wh,
    float* __restrict__ X, float* __restrict__ C,
    float* __restrict__ partf,
    const float* __restrict__ bc, const float* __restrict__ w1l,
    int tid)
{
    constexpr int G8 = G / 8;
    constexpr int KSEG = KTOT / S;
    static_assert(KTOT % S == 0, "even k-split");

    if (tid < S * G8) {
        int q = tid & (G8 - 1);
        int s = tid / G8;
        const float* xp = X + XK + s * KSEG;
        const half8* wp = (const half8*)Wh + (size_t)s * KSEG * G8 + q;
        float4 a0 = {0.f, 0.f, 0.f, 0.f};
        float4 a1 = {0.f, 0.f, 0.f, 0.f};
#pragma unroll 8
        for (int k = 0; k < KSEG; ++k) {
            float xx = xp[k];
            half8 w  = wp[(size_t)k * G8];
            a0.x = fmaf((float)w[0], xx, a0.x);
            a0.y = fmaf((float)w[1], xx, a0.y);
            a0.z = fmaf((float)w[2], xx, a0.z);
            a0.w = fmaf((float)w[3], xx, a0.w);
            a1.x = fmaf((float)w[4], xx, a1.x);
            a1.y = fmaf((float)w[5], xx, a1.y);
            a1.z = fmaf((float)w[6], xx, a1.z);
            a1.w = fmaf((float)w[7], xx, a1.w);
        }
        float4* pp = (float4*)partf + ((s * G + 8 * q) >> 2);
        pp[0] = a0;
        pp[1] = a1;
    }
    __syncthreads();   // partials visible

    if (tid < DH) {
        float g[4];
#pragma unroll
        for (int cg = 0; cg < 4; ++cg) {
            int r = cg * DH + tid;
            float acc = bc[BOFF + r];
#pragma unroll
            for (int s2 = 0; s2 < S; ++s2) acc += partf[s2 * G + r];
            if (L1X) acc = fmaf(X[0], w1l[r], acc);
            g[cg] = acc;
        }
        float ig = sigf(g[0]), fg = sigf(g[1]);
        float gg = tanhf(g[2]), og = sigf(g[3]);
        float cn = fmaf(fg, C[COFF + tid], ig * gg);
        C[COFF + tid] = cn;
        X[HOFF + tid] = og * tanhf(cn);
    }
    // trailing __syncthreads() supplied by caller
}

// ---------------- main persistent kernel: one block per batch element ----------------
// X layout: [x_t @0, h1 @1 (256), h2 @257 (128), h3 @385 (64), h4 @449 (32), h5 @481 (16)]
__global__ __launch_bounds__(1024)
void lstm_main(const float* __restrict__ inp,
               const float* __restrict__ ws,
               const float* __restrict__ w1ih,
               const float* __restrict__ wlin, const float* __restrict__ blin,
               float* __restrict__ out)
{
    __shared__ __align__(16) float X[512];
    __shared__ __align__(16) float C[512];
    __shared__ __align__(16) float part[8192];
    __shared__ float bc[1984];
    __shared__ float w1l[1024];
    __shared__ float wl[17];

    const int tid = threadIdx.x;
    const int b = blockIdx.x;

    for (int i = tid; i < 512; i += 1024) { X[i] = 0.f; C[i] = 0.f; }
    for (int i = tid; i < 1984; i += 1024) bc[i] = ws[i];
    w1l[tid] = w1ih[tid];
    if (tid < 16) wl[tid] = wlin[tid];
    if (tid == 16) wl[16] = blin[0];
    if (tid == 0) X[0] = inp[(size_t)b * TT];
    __syncthreads();

    const _Float16* Wh = (const _Float16*)(ws + H_BASE_F);

    for (int t = 0; t < TT; ++t) {
        // KTOT, G, DH, S, XK, HOFF, COFF, BOFF, L1X
        layer_step<256, 1024, 256,  8, 1,   1,   0,    0, true >(Wh + HC1, X, C, part, bc, w1l, tid);
        __syncthreads();
        layer_step<384,  512, 128, 16, 1,   257, 256, 1024, false>(Wh + HC2, X, C, part, bc, w1l, tid);
        __syncthreads();
        layer_step<192,  256,  64, 16, 257, 385, 384, 1536, false>(Wh + HC3, X, C, part, bc, w1l, tid);
        __syncthreads();
        layer_step< 96,  128,  32, 16, 385, 449, 448, 1792, false>(Wh + HC4, X, C, part, bc, w1l, tid);
        __syncthreads();
        layer_step< 48,   64,  16, 16, 449, 481, 480, 1920, false>(Wh + HC5, X, C, part, bc, w1l, tid);
        if (tid == 32) X[0] = (t + 1 < TT) ? inp[(size_t)b * TT + t + 1] : 0.f;
        __syncthreads();

        if (tid == 0) {
            float acc = wl[16];
#pragma unroll
            for (int k = 0; k < 16; ++k) acc = fmaf(X[481 + k], wl[k], acc);
            out[(size_t)b * TT + t] = acc;
        }
    }
}

extern "C" void kernel_launch(void* const* d_in, const int* in_sizes, int n_in,
                              void* d_out, int out_size, void* d_ws, size_t ws_size,
                              hipStream_t stream) {
    const float* p[23];
    for (int i = 0; i < 23 && i < n_in; ++i) p[i] = (const float*)d_in[i];
    float* ws = (float*)d_ws;

    // p: 0 inp | 1 w1ih 2 w1hh 3 b1ih 4 b1hh | 5 w2ih 6 w2hh 7 b2ih 8 b2hh |
    //    9 w3ih 10 w3hh 11 b3ih 12 b3hh | 13 w4ih 14 w4hh 15 b4ih 16 b4hh |
    //    17 w5ih 18 w5hh 19 b5ih 20 b5hh | 21 wlin 22 blin
    prep_kernel<<<dim3((PREP_TOT + 255) / 256), dim3(256), 0, stream>>>(
        p[2],
        p[5],  p[6],  p[9],  p[10], p[13], p[14], p[17], p[18],
        p[3],  p[4],  p[7],  p[8],  p[11], p[12], p[15], p[16],
        p[19], p[20],
        ws);

    lstm_main<<<dim3(BB), dim3(1024), 0, stream>>>(
        p[0], ws, p[1], p[21], p[22], (float*)d_out);
}

// Round 4
// 22344.858 us; speedup vs baseline: 8.0151x; 1.0535x over previous
//
#include <hip/hip_runtime.h>
#include <math.h>

#define TT 2048
#define NSTEP 2053   // 2048 + 4 pipeline fill + 1 linear drain

typedef _Float16 half2v __attribute__((ext_vector_type(2)));
typedef _Float16 half4v __attribute__((ext_vector_type(4)));
typedef _Float16 half8v __attribute__((ext_vector_type(8)));

#if defined(__has_builtin)
#if __has_builtin(__builtin_amdgcn_fdot2)
#define HAVE_FDOT2 1
#endif
#endif

__device__ __forceinline__ float fdot2f(half2v a, half2v b, float c) {
#ifdef HAVE_FDOT2
    return __builtin_amdgcn_fdot2(a, b, c, false);
#else
    return c + (float)a.x * (float)b.x + (float)a.y * (float)b.y;
#endif
}

__device__ __forceinline__ half2v h2at(half8v v, int m) {
    half2v r; r.x = v[2 * m]; r.y = v[2 * m + 1]; return r;
}

__device__ __forceinline__ float sigf(float x) { return 1.0f / (1.0f + __expf(-x)); }
__device__ __forceinline__ float tanh_f(float x) {
    float t = __expf(fminf(2.0f * x, 30.0f));   // exp(-inf)->0 gives -1 correctly
    return (t - 1.0f) / (t + 1.0f);
}

// ---- ws layout (bytes) ----
// [0, 253952)      board: half [2 parity][8 group][496 h][16 b]
// [262144, +2048)  flags: int, per group stride 64 ints: cnt @ g*64, rel @ g*64+32
#define FLAGS_OFF 262144
#define ZERO_F4   16512      // float4 count covering board+flags

__global__ __launch_bounds__(256)
void prep_zero(float4* ws) {
    int idx = blockIdx.x * 256 + threadIdx.x;
    if (idx < ZERO_F4) ws[idx] = make_float4(0.f, 0.f, 0.f, 0.f);
}

// One layer slice: RG h-units, 4*RG gate rows (lr = rg + RG*i, gate i, unit rg),
// K inputs read from staged X at [b*504 + KOFF + k]. KG-way k-split, J jj-iters of
// 8k each (strided-kg pattern: kk = kg*8 + jj*KG*8). Holder lane (kg==0) owns
// c/h for (unit rg, batches bg*4..bg*4+3) and writes fp16 h to the board.
template<int RG, int KG, int J, int KOFF, int K, int HBASE, bool ISL1>
__device__ __forceinline__ void layer_step(
    const _Float16* __restrict__ W, const float* __restrict__ lbias,
    const _Float16* __restrict__ Xl, _Float16* __restrict__ bdst,
    const float* __restrict__ w1x, const float* __restrict__ xin,
    float* __restrict__ cpriv, int u, int bi)
{
    constexpr int WSTR = K + 8;
    const int kg = u & (KG - 1);
    const int bg = (u / KG) & 3;
    const int rg = u / (KG * 4);

    float acc[4][4];
#pragma unroll
    for (int i = 0; i < 4; ++i)
#pragma unroll
        for (int j = 0; j < 4; ++j) acc[i][j] = 0.f;

#pragma unroll
    for (int jj = 0; jj < J; ++jj) {
        const int kk = kg * 8 + jj * (KG * 8);
        half8v xv[4], wv[4];
#pragma unroll
        for (int j = 0; j < 4; ++j)
            xv[j] = *(const half8v*)(Xl + (bg * 4 + j) * 504 + KOFF + kk);
#pragma unroll
        for (int i = 0; i < 4; ++i)
            wv[i] = *(const half8v*)(W + (rg + RG * i) * WSTR + kk);
#pragma unroll
        for (int i = 0; i < 4; ++i)
#pragma unroll
            for (int j = 0; j < 4; ++j)
#pragma unroll
                for (int m = 0; m < 4; ++m)
                    acc[i][j] = fdot2f(h2at(wv[i], m), h2at(xv[j], m), acc[i][j]);
    }

#pragma unroll
    for (int d = 1; d < KG; d <<= 1)
#pragma unroll
        for (int i = 0; i < 4; ++i)
#pragma unroll
            for (int j = 0; j < 4; ++j)
                acc[i][j] += __shfl_xor(acc[i][j], d, 64);

    if (kg == 0) {
        half4v hv;
#pragma unroll
        for (int j = 0; j < 4; ++j) {
            float g0 = acc[0][j] + lbias[rg];
            float g1 = acc[1][j] + lbias[rg + RG];
            float g2 = acc[2][j] + lbias[rg + 2 * RG];
            float g3 = acc[3][j] + lbias[rg + 3 * RG];
            if (ISL1) {
                float xt = xin[bg * 4 + j];
                g0 = fmaf(w1x[rg], xt, g0);
                g1 = fmaf(w1x[rg + RG], xt, g1);
                g2 = fmaf(w1x[rg + 2 * RG], xt, g2);
                g3 = fmaf(w1x[rg + 3 * RG], xt, g3);
            }
            float ig = sigf(g0), fg = sigf(g1), gg = tanh_f(g2), og = sigf(g3);
            float cn = fmaf(fg, cpriv[j], ig * gg);
            cpriv[j] = cn;
            hv[j] = (_Float16)(og * tanh_f(cn));
        }
        const int hglob = HBASE + bi * RG + rg;
        *(half4v*)(bdst + hglob * 16 + bg * 4) = hv;
    }
}

__global__ __launch_bounds__(512)
void lstm_pr(const float* __restrict__ inp,
             const float* __restrict__ w1ih, const float* __restrict__ w1hh,
             const float* __restrict__ b1ih, const float* __restrict__ b1hh,
             const float* __restrict__ w2ih, const float* __restrict__ w2hh,
             const float* __restrict__ b2ih, const float* __restrict__ b2hh,
             const float* __restrict__ w3ih, const float* __restrict__ w3hh,
             const float* __restrict__ b3ih, const float* __restrict__ b3hh,
             const float* __restrict__ w4ih, const float* __restrict__ w4hh,
             const float* __restrict__ b4ih, const float* __restrict__ b4hh,
             const float* __restrict__ w5ih, const float* __restrict__ w5hh,
             const float* __restrict__ b5ih, const float* __restrict__ b5hh,
             const float* __restrict__ wlin, const float* __restrict__ blin,
             float* __restrict__ out, char* __restrict__ wsb)
{
    // weights fp16, row stride K+8 (16B-aligned rows, bank stagger)
    __shared__ __align__(16) _Float16 Wl1[32 * 264];
    __shared__ __align__(16) _Float16 Wl2[16 * 392];
    __shared__ __align__(16) _Float16 Wl3[8 * 200];
    __shared__ __align__(16) _Float16 Wl4[4 * 104];
    __shared__ __align__(16) _Float16 Wl5[4 * 56];
    __shared__ __align__(16) _Float16 Xl[16 * 504];   // staged [b][h1|h2|h3|h4|h5]
    __shared__ float lbias1[32], lbias2[16], lbias3[8], lbias4[4], lbias5[4];
    __shared__ float w1x[32], wlin_s[16], blin_s, xin_s[16];

    const int tid = threadIdx.x;
    const int grp = blockIdx.x & 7;    // group ~ XCD (heuristic for locality only)
    const int bi  = blockIdx.x >> 3;   // member 0..31 within group

    // ---- init: stage weight slices fp32->fp16 into LDS ----
    for (int idx = tid; idx < 32 * 256; idx += 512) {           // L1 (w1hh)
        int lr = idx >> 8, k = idx & 255;
        int i = lr >> 3, rr = lr & 7;
        int g = i * 256 + bi * 8 + rr;
        Wl1[lr * 264 + k] = (_Float16)w1hh[g * 256 + k];
    }
    for (int idx = tid; idx < 16 * 384; idx += 512) {           // L2
        int lr = idx / 384, k = idx - lr * 384;
        int i = lr >> 2, rr = lr & 3;
        int g = i * 128 + bi * 4 + rr;
        float v = (k < 256) ? w2ih[g * 256 + k] : w2hh[g * 128 + (k - 256)];
        Wl2[lr * 392 + k] = (_Float16)v;
    }
    for (int idx = tid; idx < 8 * 192; idx += 512) {            // L3
        int lr = idx / 192, k = idx - lr * 192;
        int i = lr >> 1, rr = lr & 1;
        int g = i * 64 + bi * 2 + rr;
        float v = (k < 128) ? w3ih[g * 128 + k] : w3hh[g * 64 + (k - 128)];
        Wl3[lr * 200 + k] = (_Float16)v;
    }
    for (int idx = tid; idx < 4 * 96; idx += 512) {             // L4
        int lr = idx / 96, k = idx - lr * 96;
        int g = lr * 32 + bi;
        float v = (k < 64) ? w4ih[g * 64 + k] : w4hh[g * 32 + (k - 64)];
        Wl4[lr * 104 + k] = (_Float16)v;
    }
    if (bi < 16)
        for (int idx = tid; idx < 4 * 48; idx += 512) {         // L5
            int lr = idx / 48, k = idx - lr * 48;
            int g = lr * 16 + bi;
            float v = (k < 32) ? w5ih[g * 32 + k] : w5hh[g * 16 + (k - 32)];
            Wl5[lr * 56 + k] = (_Float16)v;
        }
    if (tid < 32) {
        int i = tid >> 3, rr = tid & 7;
        int g = i * 256 + bi * 8 + rr;
        lbias1[tid] = b1ih[g] + b1hh[g];
        w1x[tid] = w1ih[g];
    } else if (tid < 48) {
        int u = tid - 32; int i = u >> 2, rr = u & 3;
        int g = i * 128 + bi * 4 + rr;
        lbias2[u] = b2ih[g] + b2hh[g];
    } else if (tid < 56) {
        int u = tid - 48; int i = u >> 1, rr = u & 1;
        int g = i * 64 + bi * 2 + rr;
        lbias3[u] = b3ih[g] + b3hh[g];
    } else if (tid < 60) {
        int i = tid - 56; int g = i * 32 + bi;
        lbias4[i] = b4ih[g] + b4hh[g];
    } else if (tid < 64) {
        if (bi < 16) { int i = tid - 60; int g = i * 16 + bi; lbias5[i] = b5ih[g] + b5hh[g]; }
    } else if (tid < 80) {
        wlin_s[tid - 64] = wlin[tid - 64];
    } else if (tid == 80) {
        blin_s = blin[0];
    }
    __syncthreads();

    float cpriv[4] = {0.f, 0.f, 0.f, 0.f};
    _Float16* board = (_Float16*)wsb;
    int* flags = (int*)(wsb + FLAGS_OFF);
    int* cntp = flags + grp * 64;
    int* relp = flags + grp * 64 + 32;

    for (int s = 0; s < NSTEP; ++s) {
        const int pr = (s + 1) & 1, pw = s & 1;

        // ---- stage X from board[pr] (board ordering == X ordering) ----
        const _Float16* bsrc = board + (pr * 8 + grp) * (496 * 16);
#pragma unroll
        for (int it = 0; it < 16; ++it) {
            int idx = tid + it * 512;
            if (idx < 7936) {
                int h = idx >> 4, b = idx & 15;
                Xl[b * 504 + h] = bsrc[idx];
            }
        }
        if (tid < 16)
            xin_s[tid] = (s < TT) ? inp[(size_t)(grp * 16 + tid) * TT + s] : 0.f;
        __syncthreads();

        _Float16* bdst = board + (pw * 8 + grp) * (496 * 16);

        // ---- layer slices on disjoint wave-aligned thread ranges ----
        if (tid < 128) {
            if (s <= 2047)
                layer_step<8, 4, 8, 0, 256, 0, true >(Wl1, lbias1, Xl, bdst, w1x, xin_s, cpriv, tid, bi);
        } else if (tid < 256) {
            if (s >= 1 && s <= 2048)
                layer_step<4, 8, 6, 0, 384, 256, false>(Wl2, lbias2, Xl, bdst, w1x, xin_s, cpriv, tid - 128, bi);
        } else if (tid < 320) {
            if (s >= 2 && s <= 2049)
                layer_step<2, 8, 3, 256, 192, 384, false>(Wl3, lbias3, Xl, bdst, w1x, xin_s, cpriv, tid - 256, bi);
        } else if (tid < 336) {
            if (s >= 3 && s <= 2050)
                layer_step<1, 4, 3, 384, 96, 448, false>(Wl4, lbias4, Xl, bdst, w1x, xin_s, cpriv, tid - 320, bi);
        } else if (tid < 344) {
            if (bi < 16 && s >= 4 && s <= 2051)
                layer_step<1, 2, 3, 448, 48, 480, false>(Wl5, lbias5, Xl, bdst, w1x, xin_s, cpriv, tid - 336, bi);
        } else if (tid >= 416 && tid < 432) {
            if (bi == 31 && s >= 5) {
                int b = tid - 416;
                float a = blin_s;
#pragma unroll
                for (int j = 0; j < 16; ++j)
                    a += (float)Xl[b * 504 + 480 + j] * wlin_s[j];
                out[(size_t)(grp * 16 + b) * TT + (s - 5)] = a;
            }
        }

        // ---- group barrier (32 blocks), agent-scope ----
        __syncthreads();   // all board writes of this block issued & drained
        if (tid == 0) {
            int arrived = __hip_atomic_fetch_add(cntp, 1, __ATOMIC_ACQ_REL,
                                                 __HIP_MEMORY_SCOPE_AGENT);
            if (arrived == 31) {
                __hip_atomic_store(cntp, 0, __ATOMIC_RELAXED, __HIP_MEMORY_SCOPE_AGENT);
                __hip_atomic_store(relp, s + 1, __ATOMIC_RELEASE, __HIP_MEMORY_SCOPE_AGENT);
            } else {
                while (__hip_atomic_load(relp, __ATOMIC_RELAXED,
                                         __HIP_MEMORY_SCOPE_AGENT) <= s)
                    __builtin_amdgcn_s_sleep(2);
                __builtin_amdgcn_fence(__ATOMIC_ACQUIRE, "agent");
            }
        }
        __syncthreads();
    }
}

extern "C" void kernel_launch(void* const* d_in, const int* in_sizes, int n_in,
                              void* d_out, int out_size, void* d_ws, size_t ws_size,
                              hipStream_t stream) {
    const float* p[23];
    for (int i = 0; i < 23 && i < n_in; ++i) p[i] = (const float*)d_in[i];

    prep_zero<<<dim3((ZERO_F4 + 255) / 256), dim3(256), 0, stream>>>((float4*)d_ws);

    // 50.5 KB static + 32 KB dynamic pad -> 83 KB/block -> exactly 1 block/CU,
    // grid 256 = CU count -> all blocks co-resident (required for the barrier).
    lstm_pr<<<dim3(256), dim3(512), 32768, stream>>>(
        p[0],
        p[1],  p[2],  p[3],  p[4],
        p[5],  p[6],  p[7],  p[8],
        p[9],  p[10], p[11], p[12],
        p[13], p[14], p[15], p[16],
        p[17], p[18], p[19], p[20],
        p[21], p[22],
        (float*)d_out, (char*)d_ws);
}